// Round 2
// baseline (891.056 us; speedup 1.0000x reference)
//
#include <hip/hip_runtime.h>
#include <stdint.h>
#include <stddef.h>

typedef unsigned short u16;
typedef short s16x8 __attribute__((ext_vector_type(8)));
typedef unsigned short u16x4 __attribute__((ext_vector_type(4)));
typedef unsigned short u16x8 __attribute__((ext_vector_type(8)));
typedef float f32x4 __attribute__((ext_vector_type(4)));

// ---------- helpers ----------
__device__ __forceinline__ u16 f2b(float f) {
  uint32_t u = __builtin_bit_cast(uint32_t, f);
  uint32_t r = u + 0x7fffu + ((u >> 16) & 1u);   // RNE
  return (u16)(r >> 16);
}
__device__ __forceinline__ float b2f(u16 h) {
  uint32_t u = ((uint32_t)h) << 16;
  return __builtin_bit_cast(float, u);
}
__device__ __forceinline__ void gl_lds16(const void* g, void* l) {
  __builtin_amdgcn_global_load_lds((const __attribute__((address_space(1))) void*)g,
                                   (__attribute__((address_space(3))) void*)l,
                                   16, 0, 0);
}

// ---------- f32 -> bf16 casts ----------
__global__ __launch_bounds__(256) void cast_k(const float* __restrict__ in,
                                              u16* __restrict__ out, int n4) {
  int i = blockIdx.x * 256 + threadIdx.x;
  if (i >= n4) return;
  float4 v = ((const float4*)in)[i];
  u16x4 o; o[0]=f2b(v.x); o[1]=f2b(v.y); o[2]=f2b(v.z); o[3]=f2b(v.w);
  ((u16x4*)out)[i] = o;
}

// pads rows [nvalid, Nout) with zeros; in has nvalid rows of Kd floats
__global__ __launch_bounds__(256) void cast_pad_k(const float* __restrict__ in,
                                                  u16* __restrict__ out,
                                                  int Kd, int nvalid, int n4) {
  int i = blockIdx.x * 256 + threadIdx.x;
  if (i >= n4) return;
  int row = (i << 2) / Kd;
  u16x4 o;
  if (row < nvalid) {
    float4 v = ((const float4*)in)[i];
    o[0]=f2b(v.x); o[1]=f2b(v.y); o[2]=f2b(v.z); o[3]=f2b(v.w);
  } else {
    o[0]=0; o[1]=0; o[2]=0; o[3]=0;
  }
  ((u16x4*)out)[i] = o;
}

// ---------- GEMM: C[M,N] = A[M,K] * B[N,K]^T, bf16 in, f32 accum ----------
// 128x128 tile, BK=32, 4 waves, each wave 64x64 (4x4 frags of 16x16x32)
template<int OUT_BF16>
__global__ __launch_bounds__(256) void gemm_bt(const u16* __restrict__ A,
                                               const u16* __restrict__ B,
                                               void* __restrict__ Cv,
                                               int M, int N, int K) {
  __shared__ u16 As[128 * 32];
  __shared__ u16 Bs[128 * 32];
  const int t = threadIdx.x;
  const int w = t >> 6, l = t & 63;
  const int nb = N >> 7;
  const int bm = (blockIdx.x / nb) << 7;
  const int bn = (blockIdx.x % nb) << 7;
  const int wr = (w >> 1) << 6;
  const int wc = (w & 1) << 6;

  f32x4 acc[4][4];
  #pragma unroll
  for (int i = 0; i < 4; i++)
    #pragma unroll
    for (int j = 0; j < 4; j++) acc[i][j] = (f32x4){0.f, 0.f, 0.f, 0.f};

  const u16* ga = A + (size_t)(bm + w * 32 + (l >> 2)) * K + ((l & 3) * 8);
  const u16* gb = B + (size_t)(bn + w * 32 + (l >> 2)) * K + ((l & 3) * 8);
  u16* la0 = &As[(w * 32) * 32];
  u16* la1 = &As[(w * 32 + 16) * 32];
  u16* lb0 = &Bs[(w * 32) * 32];
  u16* lb1 = &Bs[(w * 32 + 16) * 32];

  for (int k0 = 0; k0 < K; k0 += 32) {
    __syncthreads();
    gl_lds16(ga, la0);
    gl_lds16(ga + (size_t)16 * K, la1);
    gl_lds16(gb, lb0);
    gl_lds16(gb + (size_t)16 * K, lb1);
    ga += 32; gb += 32;
    __syncthreads();

    s16x8 af[4], bf[4];
    #pragma unroll
    for (int i = 0; i < 4; i++) {
      af[i] = *(const s16x8*)&As[(wr + i * 16 + (l & 15)) * 32 + (l >> 4) * 8];
      bf[i] = *(const s16x8*)&Bs[(wc + i * 16 + (l & 15)) * 32 + (l >> 4) * 8];
    }
    #pragma unroll
    for (int mi = 0; mi < 4; mi++)
      #pragma unroll
      for (int ni = 0; ni < 4; ni++)
        acc[mi][ni] = __builtin_amdgcn_mfma_f32_16x16x32_bf16(af[mi], bf[ni], acc[mi][ni], 0, 0, 0);
  }

  #pragma unroll
  for (int mi = 0; mi < 4; mi++)
    #pragma unroll
    for (int ni = 0; ni < 4; ni++) {
      int row0 = bm + wr + mi * 16 + ((l >> 4) << 2);
      int col  = bn + wc + ni * 16 + (l & 15);
      #pragma unroll
      for (int r = 0; r < 4; r++) {
        float v = acc[mi][ni][r];
        if (OUT_BF16) ((u16*)Cv)[(size_t)(row0 + r) * N + col] = f2b(v);
        else          ((float*)Cv)[(size_t)(row0 + r) * N + col] = v;
      }
    }
}

// ---------- RMSNorm: Y[row, 0:D) = bf16( W * X / rms(X[0:D)) ), X stride ldx ----------
__global__ __launch_bounds__(256) void rmsnorm_k(const float* __restrict__ X,
                                                 const float* __restrict__ W,
                                                 u16* __restrict__ Y, int ldx, int D) {
  const int row = blockIdx.x;
  const float* x = X + (size_t)row * ldx;
  const int t = threadIdx.x;
  float ss = 0.f;
  for (int i = t; i < (D >> 2); i += 256) {
    float4 v = ((const float4*)x)[i];
    ss += v.x * v.x + v.y * v.y + v.z * v.z + v.w * v.w;
  }
  #pragma unroll
  for (int off = 32; off > 0; off >>= 1) ss += __shfl_xor(ss, off);
  __shared__ float red[4];
  if ((t & 63) == 0) red[t >> 6] = ss;
  __syncthreads();
  float tot = red[0] + red[1] + red[2] + red[3];
  float r = rsqrtf(tot / (float)D + 1e-6f);
  u16* y = Y + (size_t)row * D;
  for (int i = t; i < (D >> 2); i += 256) {
    float4 v = ((const float4*)x)[i];
    float4 g = ((const float4*)W)[i];
    u16x4 o;
    o[0] = f2b(v.x * r * g.x); o[1] = f2b(v.y * r * g.y);
    o[2] = f2b(v.z * r * g.z); o[3] = f2b(v.w * r * g.w);
    ((u16x4*)y)[i] = o;
  }
}

// ---------- RoPE for k_pe: read f32 CKV[:,512:576], write bf16 Kpe[4096][64] ----------
__global__ __launch_bounds__(256) void rope_kpe_k(const float* __restrict__ CKV,
                                                  u16* __restrict__ Kpe) {
  int idx = blockIdx.x * 256 + threadIdx.x;   // 4096*32 pairs
  if (idx >= 4096 * 32) return;
  int d = idx & 31;
  int m = idx >> 5;
  int s = m & 2047;
  float inv = expf(-(float)(2 * d) * (9.210340371976184f / 64.0f));  // 10000^(-2d/64)
  float ang = (float)s * inv;
  float sn, c;
  sincosf(ang, &sn, &c);
  float x1 = CKV[(size_t)m * 640 + 512 + d];
  float x2 = CKV[(size_t)m * 640 + 544 + d];
  Kpe[m * 64 + d]      = f2b(x1 * c - x2 * sn);
  Kpe[m * 64 + 32 + d] = f2b(x2 * c + x1 * sn);
}

// ---------- RoPE for q_pe, in place on Qb [4096][3072], dims h*192+128..191 ----------
__global__ __launch_bounds__(256) void rope_q_k(u16* __restrict__ Qb) {
  int idx = blockIdx.x * 256 + threadIdx.x;   // 4096*16*32 pairs
  if (idx >= 4096 * 16 * 32) return;
  int d = idx & 31;
  int h = (idx >> 5) & 15;
  int m = idx >> 9;
  int s = m & 2047;
  float inv = expf(-(float)(2 * d) * (9.210340371976184f / 64.0f));
  float ang = (float)s * inv;
  float sn, c;
  sincosf(ang, &sn, &c);
  size_t base = (size_t)m * 3072 + h * 192 + 128 + d;
  float x1 = b2f(Qb[base]);
  float x2 = b2f(Qb[base + 32]);
  Qb[base]      = f2b(x1 * c - x2 * sn);
  Qb[base + 32] = f2b(x2 * c + x1 * sn);
}

// ---------- causal flash attention ----------
// Q [4096][3072] (h*192+d, pe already rotated), KV [4096][4096] (h*256 + {k_nope:128, v:128}),
// Kpe [4096][64], O [4096][2048] (h*128+d)
__global__ __launch_bounds__(256) void attn_k(const u16* __restrict__ Q,
                                              const u16* __restrict__ KV,
                                              const u16* __restrict__ Kpe,
                                              u16* __restrict__ O) {
  const float SCALE = 0.07216878364870322f;  // 192^-0.5
  const int t = threadIdx.x, w = t >> 6, l = t & 63;
  const int qt = blockIdx.x & 31;
  const int bh = blockIdx.x >> 5;
  const int h = bh & 15, b = bh >> 4;
  const int q0 = qt << 6;
  const size_t bS = (size_t)b * 2048;

  __shared__ u16 Kf[32][200];      // 32 k-rows x 192 dims (+8 pad)
  __shared__ u16 Vt[128][40];      // 128 d-rows x 32 k (+8 pad)
  __shared__ u16 Pl[4][16][40];    // per-wave P tile

  s16x8 qf[6];
  {
    const u16* qp = Q + (bS + q0 + w * 16 + (l & 15)) * 3072 + h * 192 + ((l >> 4) * 8);
    #pragma unroll
    for (int c = 0; c < 6; c++) qf[c] = *(const s16x8*)(qp + c * 32);
  }
  float m_i[4] = {-1e30f, -1e30f, -1e30f, -1e30f};
  float l_i[4] = {0.f, 0.f, 0.f, 0.f};
  f32x4 accO[8];
  #pragma unroll
  for (int i = 0; i < 8; i++) accO[i] = (f32x4){0.f, 0.f, 0.f, 0.f};

  const int ktiles = (q0 + 64) >> 5;
  for (int kt = 0; kt < ktiles; ++kt) {
    const int k0 = kt << 5;
    __syncthreads();
    // stage K_full (k_nope + k_pe): 32 rows x 24 chunks of 8
    #pragma unroll
    for (int it = 0; it < 3; ++it) {
      int c = t + it * 256;
      int krow = c / 24, cc = c % 24;
      const u16* src = (cc < 16)
          ? KV + (bS + k0 + krow) * 4096 + h * 256 + cc * 8
          : Kpe + (bS + k0 + krow) * 64 + (cc - 16) * 8;
      *(u16x8*)&Kf[krow][cc * 8] = *(const u16x8*)src;
    }
    // stage V transposed: Vt[d][k]
    #pragma unroll
    for (int it = 0; it < 2; ++it) {
      int c = t + it * 256;
      int krow = c >> 4, dc = (c & 15) * 8;
      u16x8 v = *(const u16x8*)&KV[(bS + k0 + krow) * 4096 + h * 256 + 128 + dc];
      #pragma unroll
      for (int j = 0; j < 8; j++) Vt[dc + j][krow] = v[j];
    }
    __syncthreads();

    // scores: 16 q-rows x 32 k-cols per wave
    f32x4 sa0 = (f32x4){0.f,0.f,0.f,0.f}, sa1 = (f32x4){0.f,0.f,0.f,0.f};
    #pragma unroll
    for (int c = 0; c < 6; c++) {
      s16x8 kfa = *(const s16x8*)&Kf[(l & 15)][c * 32 + (l >> 4) * 8];
      s16x8 kfb = *(const s16x8*)&Kf[16 + (l & 15)][c * 32 + (l >> 4) * 8];
      sa0 = __builtin_amdgcn_mfma_f32_16x16x32_bf16(qf[c], kfa, sa0, 0, 0, 0);
      sa1 = __builtin_amdgcn_mfma_f32_16x16x32_bf16(qf[c], kfb, sa1, 0, 0, 0);
    }

    // online softmax (row r lives on the 16 lanes with same l>>4)
    float p0[4], p1[4];
    #pragma unroll
    for (int r = 0; r < 4; r++) {
      int qrow = q0 + w * 16 + ((l >> 4) << 2) + r;
      float s0 = sa0[r] * SCALE, s1 = sa1[r] * SCALE;
      if (k0 + (l & 15) > qrow)      s0 = -1e30f;
      if (k0 + 16 + (l & 15) > qrow) s1 = -1e30f;
      float mx = fmaxf(s0, s1);
      #pragma unroll
      for (int dd = 1; dd < 16; dd <<= 1) mx = fmaxf(mx, __shfl_xor(mx, dd));
      float mnew = fmaxf(m_i[r], mx);
      float e0 = __expf(s0 - mnew), e1 = __expf(s1 - mnew);
      float sum = e0 + e1;
      #pragma unroll
      for (int dd = 1; dd < 16; dd <<= 1) sum += __shfl_xor(sum, dd);
      float alpha = __expf(m_i[r] - mnew);
      l_i[r] = l_i[r] * alpha + sum;
      m_i[r] = mnew;
      p0[r] = e0; p1[r] = e1;
      #pragma unroll
      for (int df = 0; df < 8; df++) accO[df][r] *= alpha;
    }

    // P -> per-wave LDS (C-layout write, A-layout read)
    #pragma unroll
    for (int r = 0; r < 4; r++) {
      Pl[w][((l >> 4) << 2) + r][(l & 15)]      = f2b(p0[r]);
      Pl[w][((l >> 4) << 2) + r][16 + (l & 15)] = f2b(p1[r]);
    }
    s16x8 pf = *(const s16x8*)&Pl[w][l & 15][(l >> 4) * 8];
    #pragma unroll
    for (int df = 0; df < 8; df++) {
      s16x8 vf = *(const s16x8*)&Vt[df * 16 + (l & 15)][(l >> 4) * 8];
      accO[df] = __builtin_amdgcn_mfma_f32_16x16x32_bf16(pf, vf, accO[df], 0, 0, 0);
    }
  }

  #pragma unroll
  for (int df = 0; df < 8; df++)
    #pragma unroll
    for (int r = 0; r < 4; r++) {
      float o = accO[df][r] / l_i[r];
      O[(bS + q0 + w * 16 + ((l >> 4) << 2) + r) * 2048 + h * 128 + df * 16 + (l & 15)] = f2b(o);
    }
}

// ---------- launch ----------
extern "C" void kernel_launch(void* const* d_in, const int* in_sizes, int n_in,
                              void* d_out, int out_size, void* d_ws, size_t ws_size,
                              hipStream_t stream) {
  const float* hs    = (const float*)d_in[0];
  const float* w_qa  = (const float*)d_in[1];
  const float* q_ln  = (const float*)d_in[2];
  const float* w_qb  = (const float*)d_in[3];
  const float* w_kva = (const float*)d_in[4];
  const float* kv_ln = (const float*)d_in[5];
  const float* w_kvb = (const float*)d_in[6];
  const float* w_o   = (const float*)d_in[7];
  float* out = (float*)d_out;

  char* ws = (char*)d_ws;
  size_t off = 0;
  auto alloc = [&](size_t bytes) -> void* {
    void* p = ws + off;
    off = (off + bytes + 255) & ~(size_t)255;
    return p;
  };
  u16* Xb     = (u16*)alloc(4096ull * 2048 * 2);    // hidden bf16
  u16* Wqa    = (u16*)alloc(1536ull * 2048 * 2);
  u16* Wqb    = (u16*)alloc(3072ull * 1536 * 2);
  u16* Wkva   = (u16*)alloc(640ull * 2048 * 2);     // padded 576->640
  u16* Wkvb   = (u16*)alloc(4096ull * 512 * 2);
  u16* Wo     = (u16*)alloc(2048ull * 2048 * 2);
  float* CQraw = (float*)alloc(4096ull * 1536 * 4);
  float* CKV   = (float*)alloc(4096ull * 640 * 4);
  u16* CQn    = (u16*)alloc(4096ull * 1536 * 2);
  u16* CKVn   = (u16*)alloc(4096ull * 512 * 2);
  u16* Kpe    = (u16*)alloc(4096ull * 64 * 2);
  u16* KVb    = (u16*)alloc(4096ull * 4096 * 2);
  u16* Ob     = (u16*)alloc(4096ull * 2048 * 2);
  u16* Qb     = (u16*)CQraw;   // alias: CQraw dead once CQn is computed

  // casts
  cast_k<<<dim3(8388608 / 4 / 256), 256, 0, stream>>>(hs, Xb, 8388608 / 4);
  cast_k<<<dim3(3145728 / 4 / 256), 256, 0, stream>>>(w_qa, Wqa, 3145728 / 4);
  cast_k<<<dim3(4718592 / 4 / 256), 256, 0, stream>>>(w_qb, Wqb, 4718592 / 4);
  cast_pad_k<<<dim3(1310720 / 4 / 256), 256, 0, stream>>>(w_kva, Wkva, 2048, 576, 1310720 / 4);
  cast_k<<<dim3(2097152 / 4 / 256), 256, 0, stream>>>(w_kvb, Wkvb, 2097152 / 4);
  cast_k<<<dim3(4194304 / 4 / 256), 256, 0, stream>>>(w_o, Wo, 4194304 / 4);

  // down-projections
  gemm_bt<0><<<dim3(32 * 12), 256, 0, stream>>>(Xb, Wqa, CQraw, 4096, 1536, 2048);
  gemm_bt<0><<<dim3(32 * 5), 256, 0, stream>>>(Xb, Wkva, CKV, 4096, 640, 2048);

  // norms + k_pe rope
  rmsnorm_k<<<dim3(4096), 256, 0, stream>>>(CQraw, q_ln, CQn, 1536, 1536);
  rmsnorm_k<<<dim3(4096), 256, 0, stream>>>(CKV, kv_ln, CKVn, 640, 512);
  rope_kpe_k<<<dim3(4096 * 32 / 256), 256, 0, stream>>>(CKV, Kpe);

  // up-projections
  gemm_bt<1><<<dim3(32 * 24), 256, 0, stream>>>(CQn, Wqb, Qb, 4096, 3072, 1536);
  gemm_bt<1><<<dim3(32 * 32), 256, 0, stream>>>(CKVn, Wkvb, KVb, 4096, 4096, 512);
  rope_q_k<<<dim3(4096 * 16 * 32 / 256), 256, 0, stream>>>(Qb);

  // attention
  attn_k<<<dim3(2 * 16 * 32), 256, 0, stream>>>(Qb, KVb, Kpe, Ob);

  // output projection
  gemm_bt<0><<<dim3(32 * 16), 256, 0, stream>>>(Ob, Wo, out, 4096, 2048, 2048);
}

// Round 3
// 633.532 us; speedup vs baseline: 1.4065x; 1.4065x over previous
//
#include <hip/hip_runtime.h>
#include <stdint.h>
#include <stddef.h>

typedef unsigned short u16;
typedef short s16x8 __attribute__((ext_vector_type(8)));
typedef unsigned short u16x4 __attribute__((ext_vector_type(4)));
typedef unsigned short u16x8 __attribute__((ext_vector_type(8)));
typedef float f32x4 __attribute__((ext_vector_type(4)));

// ---------- helpers ----------
__device__ __forceinline__ u16 f2b(float f) {
  uint32_t u = __builtin_bit_cast(uint32_t, f);
  uint32_t r = u + 0x7fffu + ((u >> 16) & 1u);   // RNE
  return (u16)(r >> 16);
}
__device__ __forceinline__ float b2f(u16 h) {
  uint32_t u = ((uint32_t)h) << 16;
  return __builtin_bit_cast(float, u);
}
__device__ __forceinline__ void gl_lds16(const void* g, void* l) {
  __builtin_amdgcn_global_load_lds((const __attribute__((address_space(1))) void*)g,
                                   (__attribute__((address_space(3))) void*)l,
                                   16, 0, 0);
}

// ---------- f32 -> bf16 casts ----------
__global__ __launch_bounds__(256) void cast_k(const float* __restrict__ in,
                                              u16* __restrict__ out, int n4) {
  int i = blockIdx.x * 256 + threadIdx.x;
  if (i >= n4) return;
  float4 v = ((const float4*)in)[i];
  u16x4 o; o[0]=f2b(v.x); o[1]=f2b(v.y); o[2]=f2b(v.z); o[3]=f2b(v.w);
  ((u16x4*)out)[i] = o;
}

__global__ __launch_bounds__(256) void cast_pad_k(const float* __restrict__ in,
                                                  u16* __restrict__ out,
                                                  int Kd, int nvalid, int n4) {
  int i = blockIdx.x * 256 + threadIdx.x;
  if (i >= n4) return;
  int row = (i << 2) / Kd;
  u16x4 o;
  if (row < nvalid) {
    float4 v = ((const float4*)in)[i];
    o[0]=f2b(v.x); o[1]=f2b(v.y); o[2]=f2b(v.z); o[3]=f2b(v.w);
  } else {
    o[0]=0; o[1]=0; o[2]=0; o[3]=0;
  }
  ((u16x4*)out)[i] = o;
}

// ---------- GEMM: C[M,N] = A[M,K] * B[N,K]^T, bf16 in, f32 accum ----------
template<int OUT_BF16>
__global__ __launch_bounds__(256) void gemm_bt(const u16* __restrict__ A,
                                               const u16* __restrict__ B,
                                               void* __restrict__ Cv,
                                               int M, int N, int K) {
  __shared__ u16 As[128 * 32];
  __shared__ u16 Bs[128 * 32];
  const int t = threadIdx.x;
  const int w = t >> 6, l = t & 63;
  const int nb = N >> 7;
  const int bm = (blockIdx.x / nb) << 7;
  const int bn = (blockIdx.x % nb) << 7;
  const int wr = (w >> 1) << 6;
  const int wc = (w & 1) << 6;

  f32x4 acc[4][4];
  #pragma unroll
  for (int i = 0; i < 4; i++)
    #pragma unroll
    for (int j = 0; j < 4; j++) acc[i][j] = (f32x4){0.f, 0.f, 0.f, 0.f};

  const u16* ga = A + (size_t)(bm + w * 32 + (l >> 2)) * K + ((l & 3) * 8);
  const u16* gb = B + (size_t)(bn + w * 32 + (l >> 2)) * K + ((l & 3) * 8);
  u16* la0 = &As[(w * 32) * 32];
  u16* la1 = &As[(w * 32 + 16) * 32];
  u16* lb0 = &Bs[(w * 32) * 32];
  u16* lb1 = &Bs[(w * 32 + 16) * 32];

  for (int k0 = 0; k0 < K; k0 += 32) {
    __syncthreads();
    gl_lds16(ga, la0);
    gl_lds16(ga + (size_t)16 * K, la1);
    gl_lds16(gb, lb0);
    gl_lds16(gb + (size_t)16 * K, lb1);
    ga += 32; gb += 32;
    __syncthreads();

    s16x8 af[4], bf[4];
    #pragma unroll
    for (int i = 0; i < 4; i++) {
      af[i] = *(const s16x8*)&As[(wr + i * 16 + (l & 15)) * 32 + (l >> 4) * 8];
      bf[i] = *(const s16x8*)&Bs[(wc + i * 16 + (l & 15)) * 32 + (l >> 4) * 8];
    }
    #pragma unroll
    for (int mi = 0; mi < 4; mi++)
      #pragma unroll
      for (int ni = 0; ni < 4; ni++)
        acc[mi][ni] = __builtin_amdgcn_mfma_f32_16x16x32_bf16(af[mi], bf[ni], acc[mi][ni], 0, 0, 0);
  }

  #pragma unroll
  for (int mi = 0; mi < 4; mi++)
    #pragma unroll
    for (int ni = 0; ni < 4; ni++) {
      int row0 = bm + wr + mi * 16 + ((l >> 4) << 2);
      int col  = bn + wc + ni * 16 + (l & 15);
      #pragma unroll
      for (int r = 0; r < 4; r++) {
        float v = acc[mi][ni][r];
        if (OUT_BF16) ((u16*)Cv)[(size_t)(row0 + r) * N + col] = f2b(v);
        else          ((float*)Cv)[(size_t)(row0 + r) * N + col] = v;
      }
    }
}

// ---------- RMSNorm ----------
__global__ __launch_bounds__(256) void rmsnorm_k(const float* __restrict__ X,
                                                 const float* __restrict__ W,
                                                 u16* __restrict__ Y, int ldx, int D) {
  const int row = blockIdx.x;
  const float* x = X + (size_t)row * ldx;
  const int t = threadIdx.x;
  float ss = 0.f;
  for (int i = t; i < (D >> 2); i += 256) {
    float4 v = ((const float4*)x)[i];
    ss += v.x * v.x + v.y * v.y + v.z * v.z + v.w * v.w;
  }
  #pragma unroll
  for (int off = 32; off > 0; off >>= 1) ss += __shfl_xor(ss, off);
  __shared__ float red[4];
  if ((t & 63) == 0) red[t >> 6] = ss;
  __syncthreads();
  float tot = red[0] + red[1] + red[2] + red[3];
  float r = rsqrtf(tot / (float)D + 1e-6f);
  u16* y = Y + (size_t)row * D;
  for (int i = t; i < (D >> 2); i += 256) {
    float4 v = ((const float4*)x)[i];
    float4 g = ((const float4*)W)[i];
    u16x4 o;
    o[0] = f2b(v.x * r * g.x); o[1] = f2b(v.y * r * g.y);
    o[2] = f2b(v.z * r * g.z); o[3] = f2b(v.w * r * g.w);
    ((u16x4*)y)[i] = o;
  }
}

// ---------- RoPE for k_pe ----------
__global__ __launch_bounds__(256) void rope_kpe_k(const float* __restrict__ CKV,
                                                  u16* __restrict__ Kpe) {
  int idx = blockIdx.x * 256 + threadIdx.x;
  if (idx >= 4096 * 32) return;
  int d = idx & 31;
  int m = idx >> 5;
  int s = m & 2047;
  float inv = expf(-(float)(2 * d) * (9.210340371976184f / 64.0f));
  float ang = (float)s * inv;
  float sn, c;
  sincosf(ang, &sn, &c);
  float x1 = CKV[(size_t)m * 640 + 512 + d];
  float x2 = CKV[(size_t)m * 640 + 544 + d];
  Kpe[m * 64 + d]      = f2b(x1 * c - x2 * sn);
  Kpe[m * 64 + 32 + d] = f2b(x2 * c + x1 * sn);
}

// ---------- RoPE for q_pe ----------
__global__ __launch_bounds__(256) void rope_q_k(u16* __restrict__ Qb) {
  int idx = blockIdx.x * 256 + threadIdx.x;
  if (idx >= 4096 * 16 * 32) return;
  int d = idx & 31;
  int h = (idx >> 5) & 15;
  int m = idx >> 9;
  int s = m & 2047;
  float inv = expf(-(float)(2 * d) * (9.210340371976184f / 64.0f));
  float ang = (float)s * inv;
  float sn, c;
  sincosf(ang, &sn, &c);
  size_t base = (size_t)m * 3072 + h * 192 + 128 + d;
  float x1 = b2f(Qb[base]);
  float x2 = b2f(Qb[base + 32]);
  Qb[base]      = f2b(x1 * c - x2 * sn);
  Qb[base + 32] = f2b(x2 * c + x1 * sn);
}

// ---------- V transpose: KVb v-part [token][h*256+128+d] -> VT[bh][d=128][s=2048] ----------
__global__ __launch_bounds__(256) void vt_k(const u16* __restrict__ KV,
                                            u16* __restrict__ VT) {
  __shared__ u16 L[64][72];
  const int t = threadIdx.x;
  const int s_t = blockIdx.x & 31;
  const int d_t = (blockIdx.x >> 5) & 1;
  const int bh  = blockIdx.x >> 6;
  const int h = bh & 15, b = bh >> 4;
  const size_t bS = (size_t)b * 2048;
  const int s0 = s_t << 6, d0 = d_t << 6;

  #pragma unroll
  for (int i = 0; i < 2; i++) {
    int rs = (t >> 3) + i * 32;
    int ch = t & 7;
    u16x8 v = *(const u16x8*)&KV[(bS + s0 + rs) * 4096 + h * 256 + 128 + d0 + ch * 8];
    *(u16x8*)&L[rs][ch * 8] = v;
  }
  __syncthreads();
  #pragma unroll
  for (int i = 0; i < 2; i++) {
    int rd = (t >> 3) + i * 32;
    int ch = t & 7;
    u16x8 o;
    #pragma unroll
    for (int j = 0; j < 8; j++) o[j] = L[ch * 8 + j][rd];
    *(u16x8*)&VT[((size_t)bh * 128 + d0 + rd) * 2048 + s0 + ch * 8] = o;
  }
}

// ---------- causal flash attention, KVBLK=64, V^T from global ----------
// Q [4096][3072], KV [4096][4096] (k_nope at h*256), Kpe [4096][64],
// VT [32][128][2048], O [4096][2048]
__global__ __launch_bounds__(256, 3) void attn2_k(const u16* __restrict__ Q,
                                                  const u16* __restrict__ KV,
                                                  const u16* __restrict__ Kpe,
                                                  const u16* __restrict__ VT,
                                                  u16* __restrict__ O) {
  const float SCALE = 0.07216878364870322f;  // 192^-0.5
  const int t = threadIdx.x, w = t >> 6, l = t & 63;
  const int bh = blockIdx.x & 31;          // head-major so heavy tiles spread over CUs
  const int qt = 31 - (blockIdx.x >> 5);   // LPT: heaviest q-tiles dispatch first
  const int h = bh & 15, b = bh >> 4;
  const int q0 = qt << 6;
  const size_t bS = (size_t)b * 2048;

  __shared__ u16 Kl[64 * 192];     // 64 k-rows x 192 dims, chunk-XOR swizzled
  __shared__ u16 Pl[4][16][72];    // per-wave P tile (16 q x 64 k)

  s16x8 qf[6];
  {
    const u16* qp = Q + (bS + q0 + w * 16 + (l & 15)) * 3072 + h * 192 + ((l >> 4) * 8);
    #pragma unroll
    for (int c = 0; c < 6; c++) qf[c] = *(const s16x8*)(qp + c * 32);
  }
  float m_i[4] = {-1e30f, -1e30f, -1e30f, -1e30f};
  float l_i[4] = {0.f, 0.f, 0.f, 0.f};
  f32x4 accO[8];
  #pragma unroll
  for (int i = 0; i < 8; i++) accO[i] = (f32x4){0.f, 0.f, 0.f, 0.f};

  const u16* vb = VT + (size_t)bh * 128 * 2048;
  const int ktiles = qt + 1;

  for (int kt = 0; kt < ktiles; ++kt) {
    const int k0 = kt << 6;
    __syncthreads();   // prior tile's Kl reads done
    // stage K (k_nope|k_pe) with source-side XOR swizzle; linear LDS dest
    #pragma unroll
    for (int it = 0; it < 6; ++it) {
      int sl = it * 64 + l;                // 16B slot within this wave's 16 rows
      int r = w * 16 + sl / 24;            // tile k-row 0..63
      int cc = (sl % 24) ^ (r & 7);        // swizzled 16B chunk 0..23
      const u16* src = (cc < 16)
          ? KV + (bS + k0 + r) * 4096 + h * 256 + cc * 8
          : Kpe + (bS + k0 + r) * 64 + (cc - 16) * 8;
      gl_lds16(src, &Kl[w * 3072 + it * 512]);
    }
    __syncthreads();   // drains vmcnt: staged K visible

    // QK^T: 16 q-rows x 64 k-cols per wave
    f32x4 sa[4];
    #pragma unroll
    for (int cf = 0; cf < 4; cf++) sa[cf] = (f32x4){0.f, 0.f, 0.f, 0.f};
    #pragma unroll
    for (int c = 0; c < 6; c++) {
      #pragma unroll
      for (int cf = 0; cf < 4; cf++) {
        int row = cf * 16 + (l & 15);
        int ch = (c * 4 + (l >> 4)) ^ (row & 7);
        s16x8 kf = *(const s16x8*)&Kl[row * 192 + ch * 8];
        sa[cf] = __builtin_amdgcn_mfma_f32_16x16x32_bf16(qf[c], kf, sa[cf], 0, 0, 0);
      }
    }

    // online softmax
    const bool diag = (kt == qt);
    #pragma unroll
    for (int r = 0; r < 4; r++) {
      float s0 = sa[0][r] * SCALE, s1 = sa[1][r] * SCALE;
      float s2 = sa[2][r] * SCALE, s3 = sa[3][r] * SCALE;
      if (diag) {
        int qrow = q0 + w * 16 + ((l >> 4) << 2) + r;
        if (k0 +      (l & 15) > qrow) s0 = -1e30f;
        if (k0 + 16 + (l & 15) > qrow) s1 = -1e30f;
        if (k0 + 32 + (l & 15) > qrow) s2 = -1e30f;
        if (k0 + 48 + (l & 15) > qrow) s3 = -1e30f;
      }
      float mx = fmaxf(fmaxf(s0, s1), fmaxf(s2, s3));
      #pragma unroll
      for (int dd = 1; dd < 16; dd <<= 1) mx = fmaxf(mx, __shfl_xor(mx, dd));
      float mnew = fmaxf(m_i[r], mx);
      float e0 = __expf(s0 - mnew), e1 = __expf(s1 - mnew);
      float e2 = __expf(s2 - mnew), e3 = __expf(s3 - mnew);
      float sum = (e0 + e1) + (e2 + e3);
      #pragma unroll
      for (int dd = 1; dd < 16; dd <<= 1) sum += __shfl_xor(sum, dd);
      float alpha = __expf(m_i[r] - mnew);
      l_i[r] = l_i[r] * alpha + sum;
      m_i[r] = mnew;
      #pragma unroll
      for (int df = 0; df < 8; df++) accO[df][r] *= alpha;
      int prow = ((l >> 4) << 2) + r;
      Pl[w][prow][(l & 15)]      = f2b(e0);
      Pl[w][prow][16 + (l & 15)] = f2b(e1);
      Pl[w][prow][32 + (l & 15)] = f2b(e2);
      Pl[w][prow][48 + (l & 15)] = f2b(e3);
    }

    // PV: O += P[16x64] * V[64x128]  (V^T fragments straight from global/L2)
    #pragma unroll
    for (int sub = 0; sub < 2; sub++) {
      s16x8 pf = *(const s16x8*)&Pl[w][l & 15][sub * 32 + (l >> 4) * 8];
      #pragma unroll
      for (int df = 0; df < 8; df++) {
        s16x8 vf = *(const s16x8*)&vb[(size_t)(df * 16 + (l & 15)) * 2048 +
                                      (k0 + sub * 32 + (l >> 4) * 8)];
        accO[df] = __builtin_amdgcn_mfma_f32_16x16x32_bf16(pf, vf, accO[df], 0, 0, 0);
      }
    }
  }

  #pragma unroll
  for (int r = 0; r < 4; r++) {
    float rl = 1.0f / l_i[r];
    #pragma unroll
    for (int df = 0; df < 8; df++) {
      float o = accO[df][r] * rl;
      O[(bS + q0 + w * 16 + ((l >> 4) << 2) + r) * 2048 + h * 128 + df * 16 + (l & 15)] = f2b(o);
    }
  }
}

// ---------- launch ----------
extern "C" void kernel_launch(void* const* d_in, const int* in_sizes, int n_in,
                              void* d_out, int out_size, void* d_ws, size_t ws_size,
                              hipStream_t stream) {
  const float* hs    = (const float*)d_in[0];
  const float* w_qa  = (const float*)d_in[1];
  const float* q_ln  = (const float*)d_in[2];
  const float* w_qb  = (const float*)d_in[3];
  const float* w_kva = (const float*)d_in[4];
  const float* kv_ln = (const float*)d_in[5];
  const float* w_kvb = (const float*)d_in[6];
  const float* w_o   = (const float*)d_in[7];
  float* out = (float*)d_out;

  char* ws = (char*)d_ws;
  size_t off = 0;
  auto alloc = [&](size_t bytes) -> void* {
    void* p = ws + off;
    off = (off + bytes + 255) & ~(size_t)255;
    return p;
  };
  u16* Xb     = (u16*)alloc(4096ull * 2048 * 2);    // hidden bf16; later reused as VT
  u16* Wqa    = (u16*)alloc(1536ull * 2048 * 2);
  u16* Wqb    = (u16*)alloc(3072ull * 1536 * 2);
  u16* Wkva   = (u16*)alloc(640ull * 2048 * 2);     // padded 576->640
  u16* Wkvb   = (u16*)alloc(4096ull * 512 * 2);
  u16* Wo     = (u16*)alloc(2048ull * 2048 * 2);
  float* CQraw = (float*)alloc(4096ull * 1536 * 4);
  float* CKV   = (float*)alloc(4096ull * 640 * 4);
  u16* CQn    = (u16*)alloc(4096ull * 1536 * 2);
  u16* CKVn   = (u16*)alloc(4096ull * 512 * 2);
  u16* Kpe    = (u16*)alloc(4096ull * 64 * 2);
  u16* KVb    = (u16*)alloc(4096ull * 4096 * 2);
  u16* Ob     = (u16*)alloc(4096ull * 2048 * 2);
  u16* Qb     = (u16*)CQraw;   // alias: CQraw dead once CQn is computed
  u16* VT     = Xb;            // alias: Xb dead after down-projections (16 MB exact)

  // casts
  cast_k<<<dim3(8388608 / 4 / 256), 256, 0, stream>>>(hs, Xb, 8388608 / 4);
  cast_k<<<dim3(3145728 / 4 / 256), 256, 0, stream>>>(w_qa, Wqa, 3145728 / 4);
  cast_k<<<dim3(4718592 / 4 / 256), 256, 0, stream>>>(w_qb, Wqb, 4718592 / 4);
  cast_pad_k<<<dim3(1310720 / 4 / 256), 256, 0, stream>>>(w_kva, Wkva, 2048, 576, 1310720 / 4);
  cast_k<<<dim3(2097152 / 4 / 256), 256, 0, stream>>>(w_kvb, Wkvb, 2097152 / 4);
  cast_k<<<dim3(4194304 / 4 / 256), 256, 0, stream>>>(w_o, Wo, 4194304 / 4);

  // down-projections
  gemm_bt<0><<<dim3(32 * 12), 256, 0, stream>>>(Xb, Wqa, CQraw, 4096, 1536, 2048);
  gemm_bt<0><<<dim3(32 * 5), 256, 0, stream>>>(Xb, Wkva, CKV, 4096, 640, 2048);

  // norms + k_pe rope
  rmsnorm_k<<<dim3(4096), 256, 0, stream>>>(CQraw, q_ln, CQn, 1536, 1536);
  rmsnorm_k<<<dim3(4096), 256, 0, stream>>>(CKV, kv_ln, CKVn, 640, 512);
  rope_kpe_k<<<dim3(4096 * 32 / 256), 256, 0, stream>>>(CKV, Kpe);

  // up-projections
  gemm_bt<1><<<dim3(32 * 24), 256, 0, stream>>>(CQn, Wqb, Qb, 4096, 3072, 1536);
  gemm_bt<1><<<dim3(32 * 32), 256, 0, stream>>>(CKVn, Wkvb, KVb, 4096, 4096, 512);
  rope_q_k<<<dim3(4096 * 16 * 32 / 256), 256, 0, stream>>>(Qb);

  // V transpose (after Xb's last use)
  vt_k<<<dim3(32 * 2 * 32), 256, 0, stream>>>(KVb, VT);

  // attention
  attn2_k<<<dim3(32 * 32), 256, 0, stream>>>(Qb, KVb, Kpe, VT, Ob);

  // output projection
  gemm_bt<0><<<dim3(32 * 16), 256, 0, stream>>>(Ob, Wo, out, 4096, 2048, 2048);
}

// Round 4
// 561.575 us; speedup vs baseline: 1.5867x; 1.1281x over previous
//
#include <hip/hip_runtime.h>
#include <stdint.h>
#include <stddef.h>

typedef unsigned short u16;
typedef short s16x8 __attribute__((ext_vector_type(8)));
typedef unsigned short u16x4 __attribute__((ext_vector_type(4)));
typedef unsigned short u16x8 __attribute__((ext_vector_type(8)));
typedef float f32x4 __attribute__((ext_vector_type(4)));

// ---------- helpers ----------
__device__ __forceinline__ u16 f2b(float f) {
  uint32_t u = __builtin_bit_cast(uint32_t, f);
  uint32_t r = u + 0x7fffu + ((u >> 16) & 1u);   // RNE
  return (u16)(r >> 16);
}
__device__ __forceinline__ float b2f(u16 h) {
  uint32_t u = ((uint32_t)h) << 16;
  return __builtin_bit_cast(float, u);
}
__device__ __forceinline__ void gl_lds16(const void* g, void* l) {
  __builtin_amdgcn_global_load_lds((const __attribute__((address_space(1))) void*)g,
                                   (__attribute__((address_space(3))) void*)l,
                                   16, 0, 0);
}

// ---------- f32 -> bf16 casts ----------
__global__ __launch_bounds__(256) void cast_k(const float* __restrict__ in,
                                              u16* __restrict__ out, int n4) {
  int i = blockIdx.x * 256 + threadIdx.x;
  if (i >= n4) return;
  float4 v = ((const float4*)in)[i];
  u16x4 o; o[0]=f2b(v.x); o[1]=f2b(v.y); o[2]=f2b(v.z); o[3]=f2b(v.w);
  ((u16x4*)out)[i] = o;
}

__global__ __launch_bounds__(256) void cast_pad_k(const float* __restrict__ in,
                                                  u16* __restrict__ out,
                                                  int Kd, int nvalid, int n4) {
  int i = blockIdx.x * 256 + threadIdx.x;
  if (i >= n4) return;
  int row = (i << 2) / Kd;
  u16x4 o;
  if (row < nvalid) {
    float4 v = ((const float4*)in)[i];
    o[0]=f2b(v.x); o[1]=f2b(v.y); o[2]=f2b(v.z); o[3]=f2b(v.w);
  } else {
    o[0]=0; o[1]=0; o[2]=0; o[3]=0;
  }
  ((u16x4*)out)[i] = o;
}

// ---------- GEMM: C[M,N] = A[M,K] * B[N,K]^T, bf16 in, f32 accum ----------
// 128x128 tile, BK=32, 4 waves; XCD-swizzled grid (requires gridDim.x % 8 == 0)
template<int OUT_BF16>
__global__ __launch_bounds__(256) void gemm_bt(const u16* __restrict__ A,
                                               const u16* __restrict__ B,
                                               void* __restrict__ Cv,
                                               int M, int N, int K) {
  __shared__ u16 As[128 * 32];
  __shared__ u16 Bs[128 * 32];
  const int t = threadIdx.x;
  const int w = t >> 6, l = t & 63;
  const int nb = N >> 7;
  const int cpx = gridDim.x >> 3;
  const int swz = (blockIdx.x & 7) * cpx + (blockIdx.x >> 3);
  const int bm = (swz / nb) << 7;
  const int bn = (swz % nb) << 7;
  const int wr = (w >> 1) << 6;
  const int wc = (w & 1) << 6;

  f32x4 acc[4][4];
  #pragma unroll
  for (int i = 0; i < 4; i++)
    #pragma unroll
    for (int j = 0; j < 4; j++) acc[i][j] = (f32x4){0.f, 0.f, 0.f, 0.f};

  const u16* ga = A + (size_t)(bm + w * 32 + (l >> 2)) * K + ((l & 3) * 8);
  const u16* gb = B + (size_t)(bn + w * 32 + (l >> 2)) * K + ((l & 3) * 8);
  u16* la0 = &As[(w * 32) * 32];
  u16* la1 = &As[(w * 32 + 16) * 32];
  u16* lb0 = &Bs[(w * 32) * 32];
  u16* lb1 = &Bs[(w * 32 + 16) * 32];

  for (int k0 = 0; k0 < K; k0 += 32) {
    __syncthreads();
    gl_lds16(ga, la0);
    gl_lds16(ga + (size_t)16 * K, la1);
    gl_lds16(gb, lb0);
    gl_lds16(gb + (size_t)16 * K, lb1);
    ga += 32; gb += 32;
    __syncthreads();

    s16x8 af[4], bf[4];
    #pragma unroll
    for (int i = 0; i < 4; i++) {
      af[i] = *(const s16x8*)&As[(wr + i * 16 + (l & 15)) * 32 + (l >> 4) * 8];
      bf[i] = *(const s16x8*)&Bs[(wc + i * 16 + (l & 15)) * 32 + (l >> 4) * 8];
    }
    #pragma unroll
    for (int mi = 0; mi < 4; mi++)
      #pragma unroll
      for (int ni = 0; ni < 4; ni++)
        acc[mi][ni] = __builtin_amdgcn_mfma_f32_16x16x32_bf16(af[mi], bf[ni], acc[mi][ni], 0, 0, 0);
  }

  #pragma unroll
  for (int mi = 0; mi < 4; mi++)
    #pragma unroll
    for (int ni = 0; ni < 4; ni++) {
      int row0 = bm + wr + mi * 16 + ((l >> 4) << 2);
      int col  = bn + wc + ni * 16 + (l & 15);
      #pragma unroll
      for (int r = 0; r < 4; r++) {
        float v = acc[mi][ni][r];
        if (OUT_BF16) ((u16*)Cv)[(size_t)(row0 + r) * N + col] = f2b(v);
        else          ((float*)Cv)[(size_t)(row0 + r) * N + col] = v;
      }
    }
}

// ---------- RMSNorm ----------
__global__ __launch_bounds__(256) void rmsnorm_k(const float* __restrict__ X,
                                                 const float* __restrict__ W,
                                                 u16* __restrict__ Y, int ldx, int D) {
  const int row = blockIdx.x;
  const float* x = X + (size_t)row * ldx;
  const int t = threadIdx.x;
  float ss = 0.f;
  for (int i = t; i < (D >> 2); i += 256) {
    float4 v = ((const float4*)x)[i];
    ss += v.x * v.x + v.y * v.y + v.z * v.z + v.w * v.w;
  }
  #pragma unroll
  for (int off = 32; off > 0; off >>= 1) ss += __shfl_xor(ss, off);
  __shared__ float red[4];
  if ((t & 63) == 0) red[t >> 6] = ss;
  __syncthreads();
  float tot = red[0] + red[1] + red[2] + red[3];
  float r = rsqrtf(tot / (float)D + 1e-6f);
  u16* y = Y + (size_t)row * D;
  for (int i = t; i < (D >> 2); i += 256) {
    float4 v = ((const float4*)x)[i];
    float4 g = ((const float4*)W)[i];
    u16x4 o;
    o[0] = f2b(v.x * r * g.x); o[1] = f2b(v.y * r * g.y);
    o[2] = f2b(v.z * r * g.z); o[3] = f2b(v.w * r * g.w);
    ((u16x4*)y)[i] = o;
  }
}

// ---------- RoPE for k_pe ----------
__global__ __launch_bounds__(256) void rope_kpe_k(const float* __restrict__ CKV,
                                                  u16* __restrict__ Kpe) {
  int idx = blockIdx.x * 256 + threadIdx.x;
  if (idx >= 4096 * 32) return;
  int d = idx & 31;
  int m = idx >> 5;
  int s = m & 2047;
  float inv = expf(-(float)(2 * d) * (9.210340371976184f / 64.0f));
  float ang = (float)s * inv;
  float sn, c;
  sincosf(ang, &sn, &c);
  float x1 = CKV[(size_t)m * 640 + 512 + d];
  float x2 = CKV[(size_t)m * 640 + 544 + d];
  Kpe[m * 64 + d]      = f2b(x1 * c - x2 * sn);
  Kpe[m * 64 + 32 + d] = f2b(x2 * c + x1 * sn);
}

// ---------- RoPE for q_pe ----------
__global__ __launch_bounds__(256) void rope_q_k(u16* __restrict__ Qb) {
  int idx = blockIdx.x * 256 + threadIdx.x;
  if (idx >= 4096 * 16 * 32) return;
  int d = idx & 31;
  int h = (idx >> 5) & 15;
  int m = idx >> 9;
  int s = m & 2047;
  float inv = expf(-(float)(2 * d) * (9.210340371976184f / 64.0f));
  float ang = (float)s * inv;
  float sn, c;
  sincosf(ang, &sn, &c);
  size_t base = (size_t)m * 3072 + h * 192 + 128 + d;
  float x1 = b2f(Qb[base]);
  float x2 = b2f(Qb[base + 32]);
  Qb[base]      = f2b(x1 * c - x2 * sn);
  Qb[base + 32] = f2b(x2 * c + x1 * sn);
}

// ---------- V transpose: KVb v-part -> VT[bh][d=128][s=2048] ----------
__global__ __launch_bounds__(256) void vt_k(const u16* __restrict__ KV,
                                            u16* __restrict__ VT) {
  __shared__ u16 L[64][72];
  const int t = threadIdx.x;
  const int s_t = blockIdx.x & 31;
  const int d_t = (blockIdx.x >> 5) & 1;
  const int bh  = blockIdx.x >> 6;
  const int h = bh & 15, b = bh >> 4;
  const size_t bS = (size_t)b * 2048;
  const int s0 = s_t << 6, d0 = d_t << 6;

  #pragma unroll
  for (int i = 0; i < 2; i++) {
    int rs = (t >> 3) + i * 32;
    int ch = t & 7;
    u16x8 v = *(const u16x8*)&KV[(bS + s0 + rs) * 4096 + h * 256 + 128 + d0 + ch * 8];
    *(u16x8*)&L[rs][ch * 8] = v;
  }
  __syncthreads();
  #pragma unroll
  for (int i = 0; i < 2; i++) {
    int rd = (t >> 3) + i * 32;
    int ch = t & 7;
    u16x8 o;
    #pragma unroll
    for (int j = 0; j < 8; j++) o[j] = L[ch * 8 + j][rd];
    *(u16x8*)&VT[((size_t)bh * 128 + d0 + rd) * 2048 + s0 + ch * 8] = o;
  }
}

// ---------- causal flash attention v3 ----------
// K double-buffered (1 barrier/tile), defer-max softmax, deferred l-sum,
// V^T register-prefetched from global. KVBLK=64, 64 q-rows/block, 4 waves.
__global__ __launch_bounds__(256) void attn3_k(const u16* __restrict__ Q,
                                               const u16* __restrict__ KV,
                                               const u16* __restrict__ Kpe,
                                               const u16* __restrict__ VT,
                                               u16* __restrict__ O) {
  const float SCALE = 0.07216878364870322f;  // 192^-0.5
  const int t = threadIdx.x, w = t >> 6, l = t & 63;
  const int bh = blockIdx.x & 31;          // head-major: heavy tiles spread over CUs
  const int qt = 31 - (blockIdx.x >> 5);   // LPT: heaviest q-tiles first
  const int h = bh & 15, b = bh >> 4;
  const int q0 = qt << 6;
  const size_t bS = (size_t)b * 2048;

  __shared__ u16 Kl[2][64 * 192];   // double-buffered K tile, chunk-XOR swizzled
  __shared__ u16 Pl[4][16][72];     // per-wave P tile (16 q x 64 k)

  s16x8 qf[6];
  {
    const u16* qp = Q + (bS + q0 + w * 16 + (l & 15)) * 3072 + h * 192 + ((l >> 4) * 8);
    #pragma unroll
    for (int c = 0; c < 6; c++) qf[c] = *(const s16x8*)(qp + c * 32);
  }
  float m_i[4] = {-1e30f, -1e30f, -1e30f, -1e30f};
  float lp[4]  = {0.f, 0.f, 0.f, 0.f};          // per-lane partial row sums
  f32x4 accO[8];
  #pragma unroll
  for (int i = 0; i < 8; i++) accO[i] = (f32x4){0.f, 0.f, 0.f, 0.f};

  const u16* vbp = VT + (size_t)bh * 128 * 2048;
  const int ktiles = qt + 1;

  // stage K tile t into Kl[buf] (source-swizzled, linear LDS dest)
  auto STAGE = [&](int buf, int k0) {
    #pragma unroll
    for (int it = 0; it < 6; ++it) {
      int sl = it * 64 + l;
      int r = w * 16 + sl / 24;
      int cc = (sl % 24) ^ (r & 7);
      const u16* src = (cc < 16)
          ? KV + (bS + k0 + r) * 4096 + h * 256 + cc * 8
          : Kpe + (bS + k0 + r) * 64 + (cc - 16) * 8;
      gl_lds16(src, &Kl[buf][w * 3072 + it * 512]);
    }
  };

  STAGE(0, 0);
  __syncthreads();   // drains vmcnt(0): buf0 ready

  int cur = 0;
  for (int kt = 0; kt < ktiles; ++kt) {
    const int k0 = kt << 6;
    if (kt + 1 < ktiles) STAGE(cur ^ 1, k0 + 64);   // async prefetch next tile

    // V^T register prefetch (16 x 16B, issued before QK^T/softmax)
    s16x8 va[8], vb[8];
    #pragma unroll
    for (int df = 0; df < 8; df++)
      va[df] = *(const s16x8*)&vbp[(size_t)(df * 16 + (l & 15)) * 2048 + k0 + (l >> 4) * 8];
    #pragma unroll
    for (int df = 0; df < 8; df++)
      vb[df] = *(const s16x8*)&vbp[(size_t)(df * 16 + (l & 15)) * 2048 + k0 + 32 + (l >> 4) * 8];

    // QK^T: 16 q-rows x 64 k-cols per wave
    f32x4 sa[4];
    #pragma unroll
    for (int cf = 0; cf < 4; cf++) sa[cf] = (f32x4){0.f, 0.f, 0.f, 0.f};
    #pragma unroll
    for (int c = 0; c < 6; c++) {
      #pragma unroll
      for (int cf = 0; cf < 4; cf++) {
        int row = cf * 16 + (l & 15);
        int ch = (c * 4 + (l >> 4)) ^ (row & 7);
        s16x8 kf = *(const s16x8*)&Kl[cur][row * 192 + ch * 8];
        sa[cf] = __builtin_amdgcn_mfma_f32_16x16x32_bf16(qf[c], kf, sa[cf], 0, 0, 0);
      }
    }

    // scale + causal mask
    const bool diag = (kt == qt);
    #pragma unroll
    for (int cf = 0; cf < 4; cf++)
      #pragma unroll
      for (int r = 0; r < 4; r++) {
        float s = sa[cf][r] * SCALE;
        if (diag) {
          int qrow = q0 + w * 16 + ((l >> 4) << 2) + r;
          if (k0 + cf * 16 + (l & 15) > qrow) s = -1e30f;
        }
        sa[cf][r] = s;
      }

    // defer-max online softmax
    float lm[4];
    #pragma unroll
    for (int r = 0; r < 4; r++)
      lm[r] = fmaxf(fmaxf(sa[0][r], sa[1][r]), fmaxf(sa[2][r], sa[3][r]));
    bool safe = (lm[0] <= m_i[0] + 8.f) && (lm[1] <= m_i[1] + 8.f) &&
                (lm[2] <= m_i[2] + 8.f) && (lm[3] <= m_i[3] + 8.f);
    if (!__all(safe)) {
      #pragma unroll
      for (int r = 0; r < 4; r++) {
        float mx = lm[r];
        #pragma unroll
        for (int dd = 1; dd < 16; dd <<= 1) mx = fmaxf(mx, __shfl_xor(mx, dd));
        float mnew = fmaxf(m_i[r], mx);
        float alpha = __expf(m_i[r] - mnew);
        m_i[r] = mnew;
        lp[r] *= alpha;
        #pragma unroll
        for (int df = 0; df < 8; df++) accO[df][r] *= alpha;
      }
    }
    #pragma unroll
    for (int r = 0; r < 4; r++) {
      float e0 = __expf(sa[0][r] - m_i[r]);
      float e1 = __expf(sa[1][r] - m_i[r]);
      float e2 = __expf(sa[2][r] - m_i[r]);
      float e3 = __expf(sa[3][r] - m_i[r]);
      lp[r] += (e0 + e1) + (e2 + e3);
      int prow = ((l >> 4) << 2) + r;
      Pl[w][prow][(l & 15)]      = f2b(e0);
      Pl[w][prow][16 + (l & 15)] = f2b(e1);
      Pl[w][prow][32 + (l & 15)] = f2b(e2);
      Pl[w][prow][48 + (l & 15)] = f2b(e3);
    }

    // PV: O += P[16x64] * V[64x128]
    {
      s16x8 pf0 = *(const s16x8*)&Pl[w][l & 15][(l >> 4) * 8];
      #pragma unroll
      for (int df = 0; df < 8; df++)
        accO[df] = __builtin_amdgcn_mfma_f32_16x16x32_bf16(pf0, va[df], accO[df], 0, 0, 0);
      s16x8 pf1 = *(const s16x8*)&Pl[w][l & 15][32 + (l >> 4) * 8];
      #pragma unroll
      for (int df = 0; df < 8; df++)
        accO[df] = __builtin_amdgcn_mfma_f32_16x16x32_bf16(pf1, vb[df], accO[df], 0, 0, 0);
    }

    __syncthreads();   // drains vmcnt: next K staged; all Kl[cur] reads done
    cur ^= 1;
  }

  // final row-sum reduction (once per block) + output
  #pragma unroll
  for (int r = 0; r < 4; r++) {
    float s = lp[r];
    #pragma unroll
    for (int dd = 1; dd < 16; dd <<= 1) s += __shfl_xor(s, dd);
    float rl = 1.0f / s;
    #pragma unroll
    for (int df = 0; df < 8; df++) {
      float o = accO[df][r] * rl;
      O[(bS + q0 + w * 16 + ((l >> 4) << 2) + r) * 2048 + h * 128 + df * 16 + (l & 15)] = f2b(o);
    }
  }
}

// ---------- launch ----------
extern "C" void kernel_launch(void* const* d_in, const int* in_sizes, int n_in,
                              void* d_out, int out_size, void* d_ws, size_t ws_size,
                              hipStream_t stream) {
  const float* hs    = (const float*)d_in[0];
  const float* w_qa  = (const float*)d_in[1];
  const float* q_ln  = (const float*)d_in[2];
  const float* w_qb  = (const float*)d_in[3];
  const float* w_kva = (const float*)d_in[4];
  const float* kv_ln = (const float*)d_in[5];
  const float* w_kvb = (const float*)d_in[6];
  const float* w_o   = (const float*)d_in[7];
  float* out = (float*)d_out;

  char* ws = (char*)d_ws;
  size_t off = 0;
  auto alloc = [&](size_t bytes) -> void* {
    void* p = ws + off;
    off = (off + bytes + 255) & ~(size_t)255;
    return p;
  };
  u16* Xb     = (u16*)alloc(4096ull * 2048 * 2);    // hidden bf16; later reused as VT
  u16* Wqa    = (u16*)alloc(1536ull * 2048 * 2);
  u16* Wqb    = (u16*)alloc(3072ull * 1536 * 2);
  u16* Wkva   = (u16*)alloc(640ull * 2048 * 2);     // padded 576->640
  u16* Wkvb   = (u16*)alloc(4096ull * 512 * 2);
  u16* Wo     = (u16*)alloc(2048ull * 2048 * 2);
  float* CQraw = (float*)alloc(4096ull * 1536 * 4);
  float* CKV   = (float*)alloc(4096ull * 640 * 4);
  u16* CQn    = (u16*)alloc(4096ull * 1536 * 2);
  u16* CKVn   = (u16*)alloc(4096ull * 512 * 2);
  u16* Kpe    = (u16*)alloc(4096ull * 64 * 2);
  u16* KVb    = (u16*)alloc(4096ull * 4096 * 2);
  u16* Ob     = (u16*)alloc(4096ull * 2048 * 2);
  u16* Qb     = (u16*)CQraw;   // alias: CQraw dead once CQn is computed
  u16* VT     = Xb;            // alias: Xb dead after down-projections

  // casts
  cast_k<<<dim3(8388608 / 4 / 256), 256, 0, stream>>>(hs, Xb, 8388608 / 4);
  cast_k<<<dim3(3145728 / 4 / 256), 256, 0, stream>>>(w_qa, Wqa, 3145728 / 4);
  cast_k<<<dim3(4718592 / 4 / 256), 256, 0, stream>>>(w_qb, Wqb, 4718592 / 4);
  cast_pad_k<<<dim3(1310720 / 4 / 256), 256, 0, stream>>>(w_kva, Wkva, 2048, 576, 1310720 / 4);
  cast_k<<<dim3(2097152 / 4 / 256), 256, 0, stream>>>(w_kvb, Wkvb, 2097152 / 4);
  cast_k<<<dim3(4194304 / 4 / 256), 256, 0, stream>>>(w_o, Wo, 4194304 / 4);

  // down-projections
  gemm_bt<0><<<dim3(32 * 12), 256, 0, stream>>>(Xb, Wqa, CQraw, 4096, 1536, 2048);
  gemm_bt<0><<<dim3(32 * 5), 256, 0, stream>>>(Xb, Wkva, CKV, 4096, 640, 2048);

  // norms + k_pe rope
  rmsnorm_k<<<dim3(4096), 256, 0, stream>>>(CQraw, q_ln, CQn, 1536, 1536);
  rmsnorm_k<<<dim3(4096), 256, 0, stream>>>(CKV, kv_ln, CKVn, 640, 512);
  rope_kpe_k<<<dim3(4096 * 32 / 256), 256, 0, stream>>>(CKV, Kpe);

  // up-projections
  gemm_bt<1><<<dim3(32 * 24), 256, 0, stream>>>(CQn, Wqb, Qb, 4096, 3072, 1536);
  gemm_bt<1><<<dim3(32 * 32), 256, 0, stream>>>(CKVn, Wkvb, KVb, 4096, 4096, 512);
  rope_q_k<<<dim3(4096 * 16 * 32 / 256), 256, 0, stream>>>(Qb);

  // V transpose (after Xb's last use)
  vt_k<<<dim3(32 * 2 * 32), 256, 0, stream>>>(KVb, VT);

  // attention
  attn3_k<<<dim3(32 * 32), 256, 0, stream>>>(Qb, KVb, Kpe, VT, Ob);

  // output projection
  gemm_bt<0><<<dim3(32 * 16), 256, 0, stream>>>(Ob, Wo, out, 4096, 2048, 2048);
}